// Round 1
// baseline (337.513 us; speedup 1.0000x reference)
//
#include <hip/hip_runtime.h>
#include <hip/hip_bf16.h>

// Pipeline:
//  K0 (memsetAsync): zero stats region (sums, z, pooled)
//  K1: per-point s = x.w + b, rm = mean(x); store (s,rm); accumulate sum(s), sum(s^2) in f64
//  K2: per-point e = exp((c1*s+c2)*rm)  [softmax without max-shift: shift-invariant, values are small]
//      segment-accumulate z and pooled = segsum(x*e) with register partials (segments are sorted)
//  K3: out[b][c] = normalize( pooled[b]/(z[b]*len[b]) )

__global__ __launch_bounds__(256) void k_pass1(
    const float* __restrict__ x, const float* __restrict__ w,
    const float* __restrict__ bptr, float2* __restrict__ sr,
    double* __restrict__ sums, int N) {
  int tid = blockIdx.x * blockDim.x + threadIdx.x;
  int stride = gridDim.x * blockDim.x;
  float wreg[32];
#pragma unroll
  for (int j = 0; j < 32; ++j) wreg[j] = w[j];
  float bv = bptr[0];
  double accS = 0.0, accS2 = 0.0;
  for (int p = tid; p < N; p += stride) {
    const float4* xp = reinterpret_cast<const float4*>(x + (size_t)p * 32);
    float dot = 0.f, rsum = 0.f;
#pragma unroll
    for (int q = 0; q < 8; ++q) {
      float4 v = xp[q];
      dot += v.x * wreg[4*q] + v.y * wreg[4*q+1] + v.z * wreg[4*q+2] + v.w * wreg[4*q+3];
      rsum += (v.x + v.y) + (v.z + v.w);
    }
    float s = dot + bv;
    sr[p] = make_float2(s, rsum * 0.03125f);
    accS += (double)s;
    accS2 += (double)s * (double)s;
  }
  // wave reduce (64 lanes)
#pragma unroll
  for (int off = 32; off > 0; off >>= 1) {
    accS  += __shfl_down(accS, off, 64);
    accS2 += __shfl_down(accS2, off, 64);
  }
  __shared__ double lds[8];
  int wid = threadIdx.x >> 6;
  if ((threadIdx.x & 63) == 0) { lds[wid*2] = accS; lds[wid*2+1] = accS2; }
  __syncthreads();
  if (threadIdx.x == 0) {
    double a = 0.0, c = 0.0;
    int nw = (int)(blockDim.x >> 6);
    for (int i = 0; i < nw; ++i) { a += lds[i*2]; c += lds[i*2+1]; }
    atomicAdd(&sums[0], a);
    atomicAdd(&sums[1], c);
  }
}

__global__ __launch_bounds__(256) void k_pass2(
    const float* __restrict__ x, const float2* __restrict__ sr,
    const int* __restrict__ seg, const double* __restrict__ sums,
    const float* __restrict__ gptr, const float* __restrict__ betap,
    float* __restrict__ z, float* __restrict__ pooled,
    int N, int chunk) {
  // BN constants (uniform; cheap per-thread)
  double mu  = sums[0] / (double)N;
  double var = sums[1] / (double)N - mu * mu;
  float inv = (float)(1.0 / sqrt(var + 1e-5));
  float c1 = gptr[0] * inv;
  float c2 = betap[0] - c1 * (float)mu;

  int lane = threadIdx.x & 31;                                  // feature column
  int gid  = (blockIdx.x * blockDim.x + threadIdx.x) >> 5;      // 32-lane group id
  long p0 = (long)gid * chunk;
  long p1 = p0 + chunk; if (p1 > (long)N) p1 = N;
  if (p0 >= p1) return;

  float accP = 0.f, accZ = 0.f;
  int curSeg = seg[p0];
  for (long p = p0; p < p1; ++p) {
    int sg = seg[p];                        // uniform across the 32-lane group
    float2 s_rm = sr[p];                    // uniform
    float e = __expf((c1 * s_rm.x + c2) * s_rm.y);
    float xv = x[(size_t)p * 32 + lane];    // coalesced 128B per group
    if (sg != curSeg) {                     // rare: ~31 crossings total
      atomicAdd(&pooled[curSeg * 32 + lane], accP);
      if (lane == 0) atomicAdd(&z[curSeg], accZ);
      accP = 0.f; accZ = 0.f; curSeg = sg;
    }
    accP += xv * e;
    accZ += e;                              // only lane 0's copy is flushed
  }
  atomicAdd(&pooled[curSeg * 32 + lane], accP);
  if (lane == 0) atomicAdd(&z[curSeg], accZ);
}

__global__ void k_final(const float* __restrict__ pooled, const float* __restrict__ z,
                        const int* __restrict__ length, float* __restrict__ out, int B) {
  int tid = threadIdx.x;
  if (tid >= B * 32) return;
  int b = tid >> 5;
  float v = pooled[tid] / (z[b] * (float)length[b]);
  float sq = v * v;
#pragma unroll
  for (int off = 16; off > 0; off >>= 1) sq += __shfl_xor(sq, off, 32);
  float norm = sqrtf(sq);
  out[tid] = v / fmaxf(norm, 1e-12f);
}

extern "C" void kernel_launch(void* const* d_in, const int* in_sizes, int n_in,
                              void* d_out, int out_size, void* d_ws, size_t ws_size,
                              hipStream_t stream) {
  const float* x     = (const float*)d_in[0];
  const float* w     = (const float*)d_in[1];
  const float* b     = (const float*)d_in[2];
  const float* gamma = (const float*)d_in[3];
  const float* beta  = (const float*)d_in[4];
  const int* length  = (const int*)d_in[5];
  const int* seg     = (const int*)d_in[6];
  int N = in_sizes[6];          // 3,170,000
  int B = in_sizes[5];          // 32
  float* out = (float*)d_out;

  // workspace layout
  char* ws = (char*)d_ws;
  double* sums  = (double*)ws;                       // 2 doubles
  float*  z     = (float*)(ws + 16);                 // B floats
  float*  pooled= (float*)(ws + 16 + (size_t)B*4);   // B*32 floats
  size_t statsBytes = 16 + (size_t)B*4 + (size_t)B*32*4;
  size_t srOff = (statsBytes + 7) & ~(size_t)7;
  float2* sr = (float2*)(ws + srOff);                // N float2

  hipMemsetAsync(ws, 0, statsBytes, stream);

  const int threads = 256;
  const int blocks = 2048;                 // 8 blocks/CU, full occupancy
  k_pass1<<<blocks, threads, 0, stream>>>(x, w, b, sr, sums, N);

  int nGroups = blocks * (threads / 32);   // 16384 groups
  int chunk = (N + nGroups - 1) / nGroups; // ~194 contiguous points per group
  k_pass2<<<blocks, threads, 0, stream>>>(x, sr, seg, sums, gamma, beta, z, pooled, N, chunk);

  k_final<<<1, B * 32, 0, stream>>>(pooled, z, length, out, B);
}

// Round 2
// 259.852 us; speedup vs baseline: 1.2989x; 1.2989x over previous
//
#include <hip/hip_runtime.h>
#include <hip/hip_bf16.h>

// Layout: 8 lanes per point (each lane owns a float4 = 4 feature columns).
// A 64-lane wave covers 8 points per iteration -> 1KB contiguous per load instr.
//
//  K1 (k_stats): s = x.w + b per point (8-lane shfl reduce); global sum(s), sum(s^2) in f64.
//  K2 (k_pool):  recompute s and rowmean from x, e = exp((c1*s+c2)*rm) (no max-shift:
//                shift-invariant; |score| < ~6 so fp32-exp safe — validated R1 absmax 6e-5).
//                Register-accumulate pooled columns + z per segment (segments are sorted,
//                contiguous chunk per wave -> ~31 mid-loop flushes total); wave-reduce
//                before end flush.
//  K3 (k_final): pooled/(z*len), L2-normalize.

__global__ __launch_bounds__(256) void k_stats(
    const float* __restrict__ x, const float* __restrict__ w,
    const float* __restrict__ bptr, double* __restrict__ sums,
    int N, int chunk) {
  const int lane = threadIdx.x & 63;
  const int sub  = lane >> 3;      // which of 8 points in the batch
  const int cg   = lane & 7;       // which float4 of the point
  const float4 w4 = reinterpret_cast<const float4*>(w)[cg];
  const float bv = bptr[0];
  long gid = (long)blockIdx.x * (blockDim.x >> 6) + (threadIdx.x >> 6);
  long p0 = gid * chunk;
  long p1 = p0 + chunk; if (p1 > (long)N) p1 = N;
  double accS = 0.0, accS2 = 0.0;
  if (p0 < p1) {
    const float4* x4 = reinterpret_cast<const float4*>(x);
    for (long pb = p0; pb < p1; pb += 8) {
      long p = pb + sub;
      bool valid = (p < p1);
      long pc = valid ? p : (p1 - 1);
      float4 xv = x4[pc * 8 + cg];
      float d = fmaf(xv.x, w4.x, fmaf(xv.y, w4.y, fmaf(xv.z, w4.z, xv.w * w4.w)));
      d += __shfl_xor(d, 1);
      d += __shfl_xor(d, 2);
      d += __shfl_xor(d, 4);
      float s = d + bv;
      if (cg == 0 && valid) { accS += (double)s; accS2 += (double)s * (double)s; }
    }
  }
#pragma unroll
  for (int off = 32; off > 0; off >>= 1) {
    accS  += __shfl_down(accS, off, 64);
    accS2 += __shfl_down(accS2, off, 64);
  }
  __shared__ double lds[8];
  int wid = threadIdx.x >> 6;
  if ((threadIdx.x & 63) == 0) { lds[wid*2] = accS; lds[wid*2+1] = accS2; }
  __syncthreads();
  if (threadIdx.x == 0) {
    double a = 0.0, c = 0.0;
    int nw = (int)(blockDim.x >> 6);
    for (int i = 0; i < nw; ++i) { a += lds[i*2]; c += lds[i*2+1]; }
    atomicAdd(&sums[0], a);
    atomicAdd(&sums[1], c);
  }
}

__global__ __launch_bounds__(256) void k_pool(
    const float* __restrict__ x, const int* __restrict__ seg,
    const float* __restrict__ w, const float* __restrict__ bptr,
    const double* __restrict__ sums, const float* __restrict__ gptr,
    const float* __restrict__ betap,
    float* __restrict__ z, float* __restrict__ pooled,
    int N, int chunk) {
  double mu  = sums[0] / (double)N;
  double var = sums[1] / (double)N - mu * mu;
  float inv = (float)(1.0 / sqrt(var + 1e-5));
  float c1 = gptr[0] * inv;
  float c2 = betap[0] - c1 * (float)mu;

  const int lane = threadIdx.x & 63;
  const int sub  = lane >> 3;
  const int cg   = lane & 7;
  const float4 w4 = reinterpret_cast<const float4*>(w)[cg];
  const float bv = bptr[0];

  long gid = (long)blockIdx.x * (blockDim.x >> 6) + (threadIdx.x >> 6);
  long p0 = gid * chunk;
  long p1 = p0 + chunk; if (p1 > (long)N) p1 = N;
  if (p0 >= p1) return;

  const float4* x4 = reinterpret_cast<const float4*>(x);
  float4 acc = make_float4(0.f, 0.f, 0.f, 0.f);
  float accZ = 0.f;               // uniform within an 8-lane subgroup
  int curSeg = seg[p0];

  for (long pb = p0; pb < p1; pb += 8) {
    long p = pb + sub;
    bool valid = (p < p1);
    long pc = valid ? p : (p1 - 1);
    int sg = seg[pc];
    float4 xv = x4[pc * 8 + cg];
    float d = fmaf(xv.x, w4.x, fmaf(xv.y, w4.y, fmaf(xv.z, w4.z, xv.w * w4.w)));
    float r = (xv.x + xv.y) + (xv.z + xv.w);
    d += __shfl_xor(d, 1);  r += __shfl_xor(r, 1);
    d += __shfl_xor(d, 2);  r += __shfl_xor(r, 2);
    d += __shfl_xor(d, 4);  r += __shfl_xor(r, 4);
    float s = d + bv;
    float e = __expf((c1 * s + c2) * (r * 0.03125f));
    if (!valid) e = 0.f;
    if (sg != curSeg) {           // rare: segment boundary inside this lane's sequence
      atomicAdd(&pooled[curSeg * 32 + cg * 4 + 0], acc.x);
      atomicAdd(&pooled[curSeg * 32 + cg * 4 + 1], acc.y);
      atomicAdd(&pooled[curSeg * 32 + cg * 4 + 2], acc.z);
      atomicAdd(&pooled[curSeg * 32 + cg * 4 + 3], acc.w);
      if (cg == 0) atomicAdd(&z[curSeg], accZ);
      acc = make_float4(0.f, 0.f, 0.f, 0.f);
      accZ = 0.f;
      curSeg = sg;
    }
    acc.x = fmaf(xv.x, e, acc.x);
    acc.y = fmaf(xv.y, e, acc.y);
    acc.z = fmaf(xv.z, e, acc.z);
    acc.w = fmaf(xv.w, e, acc.w);
    accZ += e;                    // e is subgroup-uniform; only cg==0's copy is flushed
  }

  // end-of-chunk flush: combine the 8 subgroups when the wave is segment-uniform
  int seg0 = __shfl(curSeg, 0);
  if (__all(curSeg == seg0)) {
#pragma unroll
    for (int off = 8; off < 64; off <<= 1) {
      acc.x += __shfl_xor(acc.x, off);
      acc.y += __shfl_xor(acc.y, off);
      acc.z += __shfl_xor(acc.z, off);
      acc.w += __shfl_xor(acc.w, off);
      accZ  += __shfl_xor(accZ, off);
    }
    if (sub == 0) {
      atomicAdd(&pooled[curSeg * 32 + cg * 4 + 0], acc.x);
      atomicAdd(&pooled[curSeg * 32 + cg * 4 + 1], acc.y);
      atomicAdd(&pooled[curSeg * 32 + cg * 4 + 2], acc.z);
      atomicAdd(&pooled[curSeg * 32 + cg * 4 + 3], acc.w);
      if (cg == 0) atomicAdd(&z[curSeg], accZ);
    }
  } else {                        // boundary wave (rare): per-lane flush
    atomicAdd(&pooled[curSeg * 32 + cg * 4 + 0], acc.x);
    atomicAdd(&pooled[curSeg * 32 + cg * 4 + 1], acc.y);
    atomicAdd(&pooled[curSeg * 32 + cg * 4 + 2], acc.z);
    atomicAdd(&pooled[curSeg * 32 + cg * 4 + 3], acc.w);
    if (cg == 0) atomicAdd(&z[curSeg], accZ);
  }
}

__global__ void k_final(const float* __restrict__ pooled, const float* __restrict__ z,
                        const int* __restrict__ length, float* __restrict__ out, int B) {
  int tid = threadIdx.x;
  if (tid >= B * 32) return;
  int b = tid >> 5;
  float v = pooled[tid] / (z[b] * (float)length[b]);
  float sq = v * v;
#pragma unroll
  for (int off = 16; off > 0; off >>= 1) sq += __shfl_xor(sq, off, 32);
  float norm = sqrtf(sq);
  out[tid] = v / fmaxf(norm, 1e-12f);
}

extern "C" void kernel_launch(void* const* d_in, const int* in_sizes, int n_in,
                              void* d_out, int out_size, void* d_ws, size_t ws_size,
                              hipStream_t stream) {
  const float* x     = (const float*)d_in[0];
  const float* w     = (const float*)d_in[1];
  const float* b     = (const float*)d_in[2];
  const float* gamma = (const float*)d_in[3];
  const float* beta  = (const float*)d_in[4];
  const int* length  = (const int*)d_in[5];
  const int* seg     = (const int*)d_in[6];
  int N = in_sizes[6];          // 3,170,000
  int B = in_sizes[5];          // 32
  float* out = (float*)d_out;

  char* ws = (char*)d_ws;
  double* sums   = (double*)ws;                      // 2 doubles
  float*  z      = (float*)(ws + 16);                // B floats
  float*  pooled = (float*)(ws + 16 + (size_t)B*4);  // B*32 floats
  size_t statsBytes = 16 + (size_t)B*4 + (size_t)B*32*4;

  hipMemsetAsync(ws, 0, statsBytes, stream);

  const int threads = 256;
  const int blocks = 2048;                  // 8 blocks/CU
  const int nWaves = blocks * (threads / 64);          // 8192
  const int chunk = (N + nWaves - 1) / nWaves;         // ~387 points per wave

  k_stats<<<blocks, threads, 0, stream>>>(x, w, b, sums, N, chunk);
  k_pool<<<blocks, threads, 0, stream>>>(x, seg, w, b, sums, gamma, beta, z, pooled, N, chunk);
  k_final<<<1, B * 32, 0, stream>>>(pooled, z, length, out, B);
}